// Round 7
// baseline (141.151 us; speedup 1.0000x reference)
//
#include <hip/hip_runtime.h>
#include <math.h>

#define NN 256
#define NS 512
#define MS 32
#define NSTEP 32
#define VRESET 1.0f

__device__ __forceinline__ float sigf(float x) {
    // fast sigmoid: v_exp_f32 + v_rcp_f32 (~3 ulp); verified no event flips
    // (absmax identical to OCML expf version: 0.125).
    float e = __expf(-x);
    return __builtin_amdgcn_rcpf(1.0f + e);
}

// One RK4 step — op-for-op identical order to the verified kernel.
__device__ __forceinline__ void rk4step(float v, float ii, float s,
                                        float ic, float mu1, float mu2,
                                        float dt, float hh, float h6,
                                        float& vn, float& in_, float& sn)
{
    float kv1 = mu1 * (ii + ic - v);
    float ki1 = -mu2 * ii;
    float ks1 = sigf(v);
    float v2 = v + hh * kv1;
    float i2 = ii + hh * ki1;
    float kv2 = mu1 * (i2 + ic - v2);
    float ki2 = -mu2 * i2;
    float ks2 = sigf(v2);
    float v3 = v + hh * kv2;
    float i3 = ii + hh * ki2;
    float kv3 = mu1 * (i3 + ic - v3);
    float ki3 = -mu2 * i3;
    float ks3 = sigf(v3);
    float v4 = v + dt * kv3;
    float i4 = ii + dt * ki3;
    float kv4 = mu1 * (i4 + ic - v4);
    float ki4 = -mu2 * i4;
    float ks4 = sigf(v4);
    vn  = v  + h6 * (kv1 + 2.0f * kv2 + 2.0f * kv3 + kv4);
    in_ = ii + h6 * (ki1 + 2.0f * ki2 + 2.0f * ki3 + ki4);
    sn  = s  + h6 * (ks1 + 2.0f * ks2 + 2.0f * ks3 + ks4);
}

// R7: ONE WAVE (64 threads) per sample; lane owns neurons n = q*64+lane,
// q=0..3. Block consensus ("any crossed?") is a single __ballot — this
// deletes the entire rendezvous category: no barriers, no LDS flags, no
// sched_barrier pins, and crucially NO speculative RK4 (it only existed to
// cover barrier latency). Per committed step: exactly one RK4 per neuron
// (R2/R6 paid two). 4-way ILP (independent neurons, fully unrolled with
// compile-time indices) covers VALU latency on the lone wave.
// Event path, all in-wave, values identical to R6:
//  - eidx = min crossed n: per-q ballots in q-ascending order (+ctz) gives
//    the exact q*64+lane lexicographic first index; w-row load issues
//    immediately after (~30cy into resolution), L2 latency hides under the
//    argmax butterfly.
//  - argmax first-index: ordered-key map, 6-level shfl_xor max butterfly,
//    then per-q ballots of (key==max) in q order (first-max tiebreak =
//    reference argmax). Winner's s_prev/s_new fetched with 2 __shfl.
// Arithmetic is op-for-op identical per neuron => outputs bitwise identical.
__global__ __launch_bounds__(64) void snn_kernel(
    const float* __restrict__ ic_g,     // (256,)
    const float* __restrict__ w,        // (256,256)
    const float* __restrict__ mu,       // (2,)
    const float* __restrict__ v0,       // (256,)
    const float* __restrict__ i0,       // (256,)
    const float* __restrict__ s0,       // (512,256)
    const float* __restrict__ reset_s,  // (32,512,256)
    const int*   __restrict__ t1p,      // scalar
    float* __restrict__ out)
{
    const int lane = threadIdx.x;       // 0..63
    const int samp = blockIdx.x;
    const float mu1 = mu[0];
    const float mu2 = mu[1];
    const float t1f = (float)t1p[0];

    float vv[4], ii[4], ss[4], ic[4];
#pragma unroll
    for (int q = 0; q < 4; ++q) {
        const int n = q * 64 + lane;
        vv[q] = v0[n];
        ii[q] = i0[n];
        ss[q] = s0[samp * NN + n];
        ic[q] = ic_g[n];
    }
    float t0 = 0.0f;

    float* times = out;                                  // [NS][MS]
    float* vals  = out + (size_t)NS * MS;                // [NS][MS][NN][3]
    float* marks = out + (size_t)NS * MS * (1 + NN * 3); // [NS][MS][NN]

    for (int r = 0; r < MS; ++r) {
        // Prefetch this round's reset row (4x coalesced 256B); latency hides
        // under the whole step loop (no barriers anywhere to drain it).
        float rs[4];
#pragma unroll
        for (int q = 0; q < 4; ++q)
            rs[q] = reset_s[((size_t)r * NS + samp) * NN + q * 64 + lane];

        const float dt = (t1f - t0) / (float)NSTEP;
        float tev = t1f;
        float yv[4], yi[4], ys[4];
        bool  em[4] = {false, false, false, false};
        float wr[4] = {0.0f, 0.0f, 0.0f, 0.0f};
        bool  done = false;

        if (dt != 0.0f) {
            const float hh = 0.5f * dt;
            const float h6 = dt * (1.0f / 6.0f);
            float t = t0;

            for (int st = 0; st < NSTEP; ++st) {
                float vn[4], inn[4], sn[4];
#pragma unroll
                for (int q = 0; q < 4; ++q)
                    rk4step(vv[q], ii[q], ss[q], ic[q], mu1, mu2,
                            dt, hh, h6, vn[q], inn[q], sn[q]);

                const bool anyc = (sn[0] > 0.0f) | (sn[1] > 0.0f) |
                                  (sn[2] > 0.0f) | (sn[3] > 0.0f);
                if (__ballot(anyc) != 0ull) {
                    // ---- event at step st ----
                    // eidx = min crossed neuron index (q-major, then lane)
                    unsigned long long b0 = __ballot(sn[0] > 0.0f);
                    unsigned long long b1 = __ballot(sn[1] > 0.0f);
                    unsigned long long b2 = __ballot(sn[2] > 0.0f);
                    unsigned long long b3 = __ballot(sn[3] > 0.0f);
                    int eidx;
                    if (b0)      eidx =       (int)__builtin_ctzll(b0);
                    else if (b1) eidx =  64 + (int)__builtin_ctzll(b1);
                    else if (b2) eidx = 128 + (int)__builtin_ctzll(b2);
                    else         eidx = 192 + (int)__builtin_ctzll(b3);

                    // issue the w-row loads NOW; L2 latency hides under argmax
#pragma unroll
                    for (int q = 0; q < 4; ++q)
                        wr[q] = w[eidx * NN + q * 64 + lane];

                    // block argmax of sn with first-index tiebreak.
                    // ordered-key map (monotonic float -> u32)
                    unsigned k0, k1, k2, k3;
                    {
                        unsigned b;
                        b = __float_as_uint(sn[0]);
                        k0 = (b & 0x80000000u) ? ~b : (b | 0x80000000u);
                        b = __float_as_uint(sn[1]);
                        k1 = (b & 0x80000000u) ? ~b : (b | 0x80000000u);
                        b = __float_as_uint(sn[2]);
                        k2 = (b & 0x80000000u) ? ~b : (b | 0x80000000u);
                        b = __float_as_uint(sn[3]);
                        k3 = (b & 0x80000000u) ? ~b : (b | 0x80000000u);
                    }
                    unsigned ka = k0 > k1 ? k0 : k1;
                    unsigned kb = k2 > k3 ? k2 : k3;
                    unsigned red = ka > kb ? ka : kb;
#pragma unroll
                    for (int off = 32; off >= 1; off >>= 1) {
                        unsigned o = __shfl_xor(red, off);
                        red = (o > red) ? o : red;
                    }
                    // first-max index in n = q*64+lane order
                    unsigned long long c0 = __ballot(k0 == red);
                    unsigned long long c1 = __ballot(k1 == red);
                    unsigned long long c2 = __ballot(k2 == red);
                    unsigned long long c3 = __ballot(k3 == red);
                    int qw, lw;
                    if (c0)      { qw = 0; lw = (int)__builtin_ctzll(c0); }
                    else if (c1) { qw = 1; lw = (int)__builtin_ctzll(c1); }
                    else if (c2) { qw = 2; lw = (int)__builtin_ctzll(c2); }
                    else         { qw = 3; lw = (int)__builtin_ctzll(c3); }

                    // winner's s_new / s_prev (uniform lane -> broadcast)
                    float bv, bsp;
                    if (qw == 0)      { bv = __shfl(sn[0], lw); bsp = __shfl(ss[0], lw); }
                    else if (qw == 1) { bv = __shfl(sn[1], lw); bsp = __shfl(ss[1], lw); }
                    else if (qw == 2) { bv = __shfl(sn[2], lw); bsp = __shfl(ss[2], lw); }
                    else              { bv = __shfl(sn[3], lw); bsp = __shfl(ss[3], lw); }

                    float frac = bsp / (bsp - bv + 1e-12f);
                    frac = fminf(fmaxf(frac, 0.0f), 1.0f);
                    tev = t + frac * dt;
#pragma unroll
                    for (int q = 0; q < 4; ++q) {
                        yv[q] = vv[q] + frac * (vn[q]  - vv[q]);
                        yi[q] = ii[q] + frac * (inn[q] - ii[q]);
                        ys[q] = ss[q] + frac * (sn[q]  - ss[q]);
                        em[q] = sn[q] > 0.0f;
                    }
                    done = true;
                    break;
                }

                // commit the step
#pragma unroll
                for (int q = 0; q < 4; ++q) {
                    vv[q] = vn[q]; ii[q] = inn[q]; ss[q] = sn[q];
                }
                t += dt;
            }
        }

        if (!done) {
#pragma unroll
            for (int q = 0; q < 4; ++q) {
                yv[q] = vv[q]; yi[q] = ii[q]; ys[q] = ss[q];
            }
        }

        // ---- emit round outputs ----
        const int sr = samp * MS + r;
        if (lane == 0) times[sr] = tev;
#pragma unroll
        for (int q = 0; q < 4; ++q) {
            const int n = q * 64 + lane;
            float* p = vals + ((size_t)sr * NN + n) * 3;
            p[0] = yv[q];
            p[1] = yi[q];
            p[2] = ys[q];
            marks[(size_t)sr * NN + n] = em[q] ? 1.0f : 0.0f;
        }

        // ---- reset for next round ----
        if (done) {
#pragma unroll
            for (int q = 0; q < 4; ++q) {
                vv[q] = yv[q] - (em[q] ? VRESET : 0.0f);
                ii[q] = yi[q] + wr[q];
                float sres = em[q] ? rs[q] : ys[q];
                ss[q] = fminf(sres, 0.0f);
            }
        } else {
#pragma unroll
            for (int q = 0; q < 4; ++q) {
                vv[q] = yv[q];
                ii[q] = yi[q];
                ss[q] = fminf(ys[q], 0.0f);
            }
        }
        t0 = tev;
    }
}

extern "C" void kernel_launch(void* const* d_in, const int* in_sizes, int n_in,
                              void* d_out, int out_size, void* d_ws, size_t ws_size,
                              hipStream_t stream) {
    const float* ic      = (const float*)d_in[0];
    const float* w       = (const float*)d_in[1];
    const float* mu      = (const float*)d_in[2];
    const float* v0      = (const float*)d_in[3];
    const float* i0      = (const float*)d_in[4];
    const float* s0      = (const float*)d_in[5];
    const float* reset_s = (const float*)d_in[6];
    const int*   t1p     = (const int*)d_in[7];
    float* out = (float*)d_out;

    snn_kernel<<<dim3(NS), dim3(64), 0, stream>>>(ic, w, mu, v0, i0, s0,
                                                  reset_s, t1p, out);
}

// Round 9
// 133.980 us; speedup vs baseline: 1.0535x; 1.0535x over previous
//
#include <hip/hip_runtime.h>
#include <math.h>

#define NN 256
#define NS 512
#define MS 32
#define NSTEP 32
#define VRESET 1.0f

__device__ __forceinline__ float sigf(float x) {
    // fast sigmoid: v_exp_f32 + v_rcp_f32 (~3 ulp); verified no event flips
    // (absmax identical to OCML expf version: 0.125).
    float e = __expf(-x);
    return __builtin_amdgcn_rcpf(1.0f + e);
}

// Barrier WITHOUT the vmcnt(0) drain that __syncthreads() emits.
// LDS-only visibility; global stores/loads deliberately stay in flight.
__device__ __forceinline__ void block_sync_lds() {
    asm volatile("s_waitcnt lgkmcnt(0)" ::: "memory");
    __builtin_amdgcn_s_barrier();
    asm volatile("" ::: "memory");
}

// One RK4 step — op-for-op identical order to the verified kernel.
__device__ __forceinline__ void rk4step(float v, float ii, float s,
                                        float ic, float mu1, float mu2,
                                        float dt, float hh, float h6,
                                        float& vn, float& in_, float& sn)
{
    float kv1 = mu1 * (ii + ic - v);
    float ki1 = -mu2 * ii;
    float ks1 = sigf(v);
    float v2 = v + hh * kv1;
    float i2 = ii + hh * ki1;
    float kv2 = mu1 * (i2 + ic - v2);
    float ki2 = -mu2 * i2;
    float ks2 = sigf(v2);
    float v3 = v + hh * kv2;
    float i3 = ii + hh * ki2;
    float kv3 = mu1 * (i3 + ic - v3);
    float ki3 = -mu2 * i3;
    float ks3 = sigf(v3);
    float v4 = v + dt * kv3;
    float i4 = ii + dt * ki3;
    float kv4 = mu1 * (i4 + ic - v4);
    float ki4 = -mu2 * i4;
    float ks4 = sigf(v4);
    vn  = v  + h6 * (kv1 + 2.0f * kv2 + 2.0f * kv3 + kv4);
    in_ = ii + h6 * (ki1 + 2.0f * ki2 + 2.0f * ki3 + ki4);
    sn  = s  + h6 * (ks1 + 2.0f * ks2 + 2.0f * ks3 + ks4);
}

// One block (256 threads = 4 waves) per sample; thread tid owns neuron tid.
// R8 = R6 champion skeleton (R7's 1-wave variant regressed: the common
// ~3.5k cy/round stall is structure-independent; R6's 8 waves/CU cover it
// best) + three round-boundary latency changes, all value-identical:
//  1. reset_s prefetched ONE ROUND AHEAD (register dbuf) — issue-to-use
//     distance ~4k cy, fully burying the HBM-cold ~900cy row fetch that a
//     same-round prefetch only partially covers.
//  2. s_setprio(1) over the post-barrier critical window (flag read ->
//     event resolve -> reset math); 0 during bulk integration/emit. Two
//     co-resident blocks sit at random phase skew: this steers the SIMD
//     toward whichever block is in its serial resolve chain.
//  3. reset-state computed BEFORE output emit at round end: round r+1's
//     chain head is earliest in program order; stores drift off-chain.
__global__ __launch_bounds__(256) void snn_kernel(
    const float* __restrict__ ic_g,     // (256,)
    const float* __restrict__ w,        // (256,256)
    const float* __restrict__ mu,       // (2,)
    const float* __restrict__ v0,       // (256,)
    const float* __restrict__ i0,       // (256,)
    const float* __restrict__ s0,       // (512,256)
    const float* __restrict__ reset_s,  // (32,512,256)
    const int*   __restrict__ t1p,      // scalar
    float* __restrict__ out)
{
    const int tid  = threadIdx.x;   // neuron index
    const int lane = tid & 63;
    const int wid  = tid >> 6;
    const int samp = blockIdx.x;
    const float mu1 = mu[0];
    const float mu2 = mu[1];
    const float t1f = (float)t1p[0];

    __shared__ int4 s_flag[4];                     // per-step meta, st&3 rot
    __shared__ __align__(16) float s_sn[2][NN];    // cs, round-parity dbuf
    __shared__ __align__(16) float s_sp[2][NN];    // ps, round-parity dbuf

    float v  = v0[tid];
    float ii = i0[tid];
    float s  = s0[samp * NN + tid];
    const float ic = ic_g[tid];
    float t0 = 0.0f;

    // reset_s row for round 0 (cold HBM; issued ~one full round before use)
    float rs_cur = reset_s[(size_t)samp * NN + tid];

    float* times = out;                                  // [NS][MS]
    float* vals  = out + (size_t)NS * MS;                // [NS][MS][NN][3]
    float* marks = out + (size_t)NS * MS * (1 + NN * 3); // [NS][MS][NN]

    for (int r = 0; r < MS; ++r) {
        const int buf = r & 1;
        // Prefetch NEXT round's reset row now (~4k cy ahead of its use).
        const int rn = (r + 1 < MS) ? (r + 1) : r;
        const float rs_nxt = reset_s[((size_t)rn * NS + samp) * NN + tid];

        const float dt = (t1f - t0) / (float)NSTEP;
        float tev = t1f;
        float yv = v, yi = ii, ys = s;
        bool  em = false;
        bool  done = false;
        float wr = 0.0f;

        if (dt != 0.0f) {
            const float hh = 0.5f * dt;
            const float h6 = dt * (1.0f / 6.0f);

            // pipeline: P = y_st, C = y_{st+1}
            float pv = v, pi_ = ii, ps = s;
            float cv, ci, cs;
            rk4step(pv, pi_, ps, ic, mu1, mu2, dt, hh, h6, cv, ci, cs);
            float t = t0;

            for (int st = 0; st < NSTEP; ++st) {
                // 1) publish step-st data: per-neuron cs/ps + per-wave meta
                s_sn[buf][tid] = cs;
                s_sp[buf][tid] = ps;
                unsigned long long bl = __ballot(cs > 0.0f);
                if (lane == 0) {
                    int meta = (bl != 0ull)
                        ? ((((wid << 6) + (int)__builtin_ctzll(bl)) << 1) | 1)
                        : 0;
                    ((int*)&s_flag[st & 3])[wid] = meta;
                }

                // 2a) spec y_{st+2} first half — covers ds_write drain+barrier
                float kv1 = mu1 * (ci + ic - cv);
                float ki1 = -mu2 * ci;
                float ks1 = sigf(cv);
                float v2 = cv + hh * kv1;
                float i2 = ci + hh * ki1;
                float kv2 = mu1 * (i2 + ic - v2);
                float ki2 = -mu2 * i2;
                float ks2 = sigf(v2);

                __builtin_amdgcn_sched_barrier(0);
                block_sync_lds();
                __builtin_amdgcn_s_setprio(1);   // post-barrier resolve is
                                                 // the serial chain: prefer
                                                 // this block on the SIMD
                __builtin_amdgcn_sched_barrier(0);

                // 3) flag read (uniform addr -> broadcast ds_read_b128)...
                int4 f = s_flag[st & 3];

                // 2b) ...covered by spec second half
                float v3 = cv + hh * kv2;
                float i3 = ci + hh * ki2;
                float kv3 = mu1 * (i3 + ic - v3);
                float ki3 = -mu2 * i3;
                float ks3 = sigf(v3);
                float v4 = cv + dt * kv3;
                float i4 = ci + dt * ki3;
                float kv4 = mu1 * (i4 + ic - v4);
                float ki4 = -mu2 * i4;
                float ks4 = sigf(v4);
                float nv  = cv + h6 * (kv1 + 2.0f * kv2 + 2.0f * kv3 + kv4);
                float ni  = ci + h6 * (ki1 + 2.0f * ki2 + 2.0f * ki3 + ki4);
                float ns_ = cs + h6 * (ks1 + 2.0f * ks2 + 2.0f * ks3 + ks4);

                if ((f.x | f.y | f.z | f.w) & 1) {
                    // ---- event at step st ----
                    // issue the 256-value argmax read early
                    const float4 q =
                        *(const float4*)&s_sn[buf][lane << 2];
                    // eidx straight from metas; issue w-row load NOW
                    int e0 = (f.x & 1) ? (f.x >> 1) : (2 * NN);
                    int e1 = (f.y & 1) ? (f.y >> 1) : (2 * NN);
                    int e2 = (f.z & 1) ? (f.z >> 1) : (2 * NN);
                    int e3 = (f.w & 1) ? (f.w >> 1) : (2 * NN);
                    int ea = e0 < e1 ? e0 : e1;
                    int eb = e2 < e3 ? e2 : e3;
                    int eidx = ea < eb ? ea : eb;
                    wr = w[eidx * NN + tid];

                    // block argmax (identical redundant reduce in each wave):
                    // ordered-key map (monotonic float->u32)
                    unsigned bx = __float_as_uint(q.x);
                    unsigned by = __float_as_uint(q.y);
                    unsigned bz = __float_as_uint(q.z);
                    unsigned bw = __float_as_uint(q.w);
                    unsigned k0 = (bx & 0x80000000u) ? ~bx : (bx | 0x80000000u);
                    unsigned k1 = (by & 0x80000000u) ? ~by : (by | 0x80000000u);
                    unsigned k2 = (bz & 0x80000000u) ? ~bz : (bz | 0x80000000u);
                    unsigned k3 = (bw & 0x80000000u) ? ~bw : (bw | 0x80000000u);
                    unsigned km = k0; int pos = 0;
                    if (k1 > km) { km = k1; pos = 1; }   // strict >: first max
                    if (k2 > km) { km = k2; pos = 2; }
                    if (k3 > km) { km = k3; pos = 3; }
                    unsigned red = km;
#pragma unroll
                    for (int off = 32; off >= 1; off >>= 1) {
                        unsigned o = __shfl_xor(red, off);
                        red = (o > red) ? o : red;
                    }
                    unsigned long long cm = __ballot(km == red);
                    int L = (int)__builtin_ctzll(cm);        // lowest lane
                    int wpos = __builtin_amdgcn_readlane(pos, L);
                    int bn = (L << 2) + wpos;                // first-max idx

                    float bv  = s_sn[buf][bn];
                    float bsp = s_sp[buf][bn];
                    float frac = bsp / (bsp - bv + 1e-12f);
                    frac = fminf(fmaxf(frac, 0.0f), 1.0f);
                    tev = t + frac * dt;
                    yv = pv  + frac * (cv - pv);
                    yi = pi_ + frac * (ci - pi_);
                    ys = ps  + frac * (cs - ps);
                    em = (cs > 0.0f);
                    done = true;
                    break;
                }
                __builtin_amdgcn_s_setprio(0);   // bulk integration resumes

                // 4) advance pipeline (guarded: no-event rounds end at y_32)
                if (st + 1 < NSTEP) {
                    pv = cv; pi_ = ci; ps = cs;
                    cv = nv; ci = ni; cs = ns_;
                    t += dt;
                }
            }

            if (!done) { yv = cv; yi = ci; ys = cs; }  // y_32, no event
        }

        // ---- reset for next round FIRST (round r+1's chain head) ----
        if (done) {
            v  = yv - (em ? VRESET : 0.0f);
            ii = yi + wr;
            float sres = em ? rs_cur : ys;
            s = fminf(sres, 0.0f);
        } else {
            v = yv; ii = yi;
            s = fminf(ys, 0.0f);
        }
        t0 = tev;
        __builtin_amdgcn_s_setprio(0);   // emit is off-chain

        // ---- emit round outputs (stores stay in flight across barriers) ----
        const int sr = samp * MS + r;
        if (tid == 0) times[sr] = tev;
        {
            float* p = vals + ((size_t)sr * NN + tid) * 3;
            p[0] = yv;
            p[1] = yi;
            p[2] = ys;
            marks[(size_t)sr * NN + tid] = em ? 1.0f : 0.0f;
        }

        rs_cur = rs_nxt;   // advance the reset_s double-buffer
    }
}

extern "C" void kernel_launch(void* const* d_in, const int* in_sizes, int n_in,
                              void* d_out, int out_size, void* d_ws, size_t ws_size,
                              hipStream_t stream) {
    const float* ic      = (const float*)d_in[0];
    const float* w       = (const float*)d_in[1];
    const float* mu      = (const float*)d_in[2];
    const float* v0      = (const float*)d_in[3];
    const float* i0      = (const float*)d_in[4];
    const float* s0      = (const float*)d_in[5];
    const float* reset_s = (const float*)d_in[6];
    const int*   t1p     = (const int*)d_in[7];
    float* out = (float*)d_out;

    snn_kernel<<<dim3(NS), dim3(256), 0, stream>>>(ic, w, mu, v0, i0, s0,
                                                   reset_s, t1p, out);
}